// Round 4
// baseline (315.092 us; speedup 1.0000x reference)
//
#include <hip/hip_runtime.h>
#include <hip/hip_cooperative_groups.h>

namespace cg = cooperative_groups;

// B=2, N=2048, E=32768, Fin=256, nhead=8, nhid=8 (C1=64), Fout=64. All f32.
#define BB   2
#define NN   2048
#define FIN  256
#define HH   8
#define NHID 8
#define C1   64
#define FOUT 64
#define MAXD 192   // fixed CSR row capacity (Poisson(16) max over 2048 rows ~45)
#define NB   256   // grid blocks (1 per CU -> co-resident)
#define TPB  256

// ===========================================================================
// Phase bodies (shared between the cooperative kernel and the fallback path)
// ===========================================================================

// P0: zero cnt + h1 = x @ W_h (+ fused s1/s2). 16 nodes/block, 4/wave.
__device__ __forceinline__
void phase_gemm1(const float* __restrict__ x, const float* __restrict__ Wh,
                 const float* __restrict__ ah, float* __restrict__ h1,
                 float* __restrict__ s1h, float* __restrict__ s2h,
                 int* __restrict__ cnt, float (*xs)[FIN])
{
    int tid = threadIdx.x;
    int gtid = blockIdx.x * TPB + tid;
    if (gtid < NN) cnt[gtid] = 0;

    int base = blockIdx.x * 16;
    const float4* xv = (const float4*)(x + (size_t)base * FIN);
    float4* xsv = (float4*)&xs[0][0];
#pragma unroll
    for (int i = 0; i < 4; ++i) xsv[tid + TPB * i] = xv[tid + TPB * i];
    __syncthreads();

    int wave = tid >> 6, lane = tid & 63;
    int head = lane >> 3, k = lane & 7;
    const float* Wp = Wh + head * FIN * NHID + k;
    int n0 = wave * 4;
    float a0 = 0.f, a1 = 0.f, a2 = 0.f, a3 = 0.f;
#pragma unroll 4
    for (int f = 0; f < FIN; ++f) {
        float wv = Wp[f * NHID];
        a0 += wv * xs[n0 + 0][f];
        a1 += wv * xs[n0 + 1][f];
        a2 += wv * xs[n0 + 2][f];
        a3 += wv * xs[n0 + 3][f];
    }
    size_t hb = (size_t)(base + n0) * C1 + lane;
    h1[hb] = a0; h1[hb + C1] = a1; h1[hb + 2 * C1] = a2; h1[hb + 3 * C1] = a3;

    float c1 = ah[head * 16 + k], c2 = ah[head * 16 + 8 + k];
    float p0 = a0 * c1, p1 = a1 * c1, p2 = a2 * c1, p3 = a3 * c1;
    float q0 = a0 * c2, q1 = a1 * c2, q2 = a2 * c2, q3 = a3 * c2;
    for (int o = 1; o < 8; o <<= 1) {
        p0 += __shfl_xor(p0, o); p1 += __shfl_xor(p1, o);
        p2 += __shfl_xor(p2, o); p3 += __shfl_xor(p3, o);
        q0 += __shfl_xor(q0, o); q1 += __shfl_xor(q1, o);
        q2 += __shfl_xor(q2, o); q3 += __shfl_xor(q3, o);
    }
    if (k == 0) {
        float ps[4] = {p0, p1, p2, p3}, qs[4] = {q0, q1, q2, q3};
#pragma unroll
        for (int j = 0; j < 4; ++j) {
            int bn = base + n0 + j;
            int b = bn >> 11, n = bn & (NN - 1);
            s1h[(b * HH + head) * NN + n] = ps[j];
            s2h[(b * HH + head) * NN + n] = qs[j];
        }
    }
}

// P1: scatter edges into fixed-stride CSR rows (duplicates kept; dedup later).
__device__ __forceinline__
void phase_scatter(const int* __restrict__ edges, int E,
                   int* __restrict__ cnt, int* __restrict__ csr)
{
    int gtid = blockIdx.x * TPB + threadIdx.x;
    for (int e = gtid; e < E; e += NB * TPB) {
        int s = edges[e], t = edges[E + e];
        int pos = atomicAdd(&cnt[s], 1);
        if (pos < MAXD) csr[s * MAXD + pos] = t;
    }
}

// P2: layer-1 sparse attention (local dedup) + elu + gemm2 + s1o/s2o.
// 16 nodes/block, 1 wave per node x 4 iterations; LDS regions wave-private.
__device__ __forceinline__
void phase_att1(const float* __restrict__ h1, const float* __restrict__ s1h,
                const float* __restrict__ s2h, const float* __restrict__ bh,
                const int* __restrict__ cnt, const int* __restrict__ csr,
                const float* __restrict__ Wo, const float* __restrict__ ao,
                float* __restrict__ h2, float* __restrict__ s1o,
                float* __restrict__ s2o, char* sh)
{
    int tid = threadIdx.x, w = tid >> 6, lane = tid & 63;
    int* tgW = (int*)sh + w * MAXD;                               // [0,3072)
    unsigned char* dupW = (unsigned char*)(sh + 4 * 4 * MAXD) + w * MAXD; // [3072,3840)
    float* xsW = (float*)(sh + 4096) + w * C1;                    // [4096,5120)
    int head = lane >> 3;

    for (int j = 0; j < 4; ++j) {
        int bn = blockIdx.x * 16 + j * 4 + w;
        int b = bn >> 11, n = bn & (NN - 1);
        int d = cnt[n]; if (d > MAXD) d = MAXD;
        for (int l = lane; l < d; l += 64) tgW[l] = csr[n * MAXD + l];
        __syncthreads();
        for (int l = lane; l < d; l += 64) {
            int t = tgW[l], f = 0;
            for (int jj = 0; jj < l; ++jj) f |= (tgW[jj] == t);
            dupW[l] = (unsigned char)f;
        }
        __syncthreads();

        const float* hp = h1 + (size_t)b * NN * C1 + lane;
        float out;
        if (d == 0) {  // dense -1e20 row -> uniform softmax over all N
            float acc = 0.f;
            for (int jj = 0; jj < NN; ++jj) acc += hp[(size_t)jj * C1];
            out = acc * (1.0f / NN);
        } else {
            float s1 = s1h[(b * HH + head) * NN + n];
            const float* s2p = s2h + (b * HH + head) * NN;
            float m = -3.4e38f;
            for (int p = 0; p < d; ++p) {
                if (dupW[p]) continue;
                float ee = s1 + s2p[tgW[p]];
                ee = ee > 0.f ? ee : 0.2f * ee;
                m = fmaxf(m, ee);
            }
            float den = 0.f, acc = 0.f;
            for (int p = 0; p < d; ++p) {
                if (dupW[p]) continue;
                int t = tgW[p];
                float ee = s1 + s2p[t];
                ee = ee > 0.f ? ee : 0.2f * ee;
                float wt = expf(ee - m);
                den += wt;
                acc += wt * hp[(size_t)t * C1];
            }
            out = acc / den;
        }
        out += bh[lane];
        xsW[lane] = out > 0.f ? out : (expf(out) - 1.f);   // elu
        __syncthreads();

        float acc2 = 0.f;
#pragma unroll 16
        for (int f = 0; f < C1; ++f) acc2 += xsW[f] * Wo[f * FOUT + lane];
        h2[(size_t)bn * FOUT + lane] = acc2;
        float p = acc2 * ao[lane];
        float q = acc2 * ao[FOUT + lane];
        for (int o = 1; o < 64; o <<= 1) { p += __shfl_xor(p, o); q += __shfl_xor(q, o); }
        if (lane == 0) { s1o[bn] = p; s2o[bn] = q; }
    }
}

// P3: layer-2 sparse attention (local dedup) -> out2.
__device__ __forceinline__
void phase_att2(const float* __restrict__ h2, const float* __restrict__ s1o,
                const float* __restrict__ s2o, const float* __restrict__ bo,
                const int* __restrict__ cnt, const int* __restrict__ csr,
                float* __restrict__ out2, char* sh)
{
    int tid = threadIdx.x, w = tid >> 6, lane = tid & 63;
    int* tgW = (int*)sh + w * MAXD;
    unsigned char* dupW = (unsigned char*)(sh + 4 * 4 * MAXD) + w * MAXD;

    for (int j = 0; j < 4; ++j) {
        int bn = blockIdx.x * 16 + j * 4 + w;
        int b = bn >> 11, n = bn & (NN - 1);
        int d = cnt[n]; if (d > MAXD) d = MAXD;
        for (int l = lane; l < d; l += 64) tgW[l] = csr[n * MAXD + l];
        __syncthreads();
        for (int l = lane; l < d; l += 64) {
            int t = tgW[l], f = 0;
            for (int jj = 0; jj < l; ++jj) f |= (tgW[jj] == t);
            dupW[l] = (unsigned char)f;
        }
        __syncthreads();

        const float* hp = h2 + (size_t)b * NN * FOUT + lane;
        float out;
        if (d == 0) {
            float acc = 0.f;
            for (int jj = 0; jj < NN; ++jj) acc += hp[(size_t)jj * FOUT];
            out = acc * (1.0f / NN);
        } else {
            float s1 = s1o[bn];
            const float* s2p = s2o + b * NN;
            float m = -3.4e38f;
            for (int p = 0; p < d; ++p) {
                if (dupW[p]) continue;
                float ee = s1 + s2p[tgW[p]];
                ee = ee > 0.f ? ee : 0.2f * ee;
                m = fmaxf(m, ee);
            }
            float den = 0.f, acc = 0.f;
            for (int p = 0; p < d; ++p) {
                if (dupW[p]) continue;
                int t = tgW[p];
                float ee = s1 + s2p[t];
                ee = ee > 0.f ? ee : 0.2f * ee;
                float wt = expf(ee - m);
                den += wt;
                acc += wt * hp[(size_t)t * FOUT];
            }
            out = acc / den;
        }
        out2[(size_t)bn * FOUT + lane] = out + bo[lane];
    }
}

// P4: fused logsumexp over node axis + subtract + store. blocks 0..127 active.
__device__ __forceinline__
void phase_lse(const float* __restrict__ out2, float* __restrict__ out, char* sh)
{
    if (blockIdx.x >= BB * FOUT) return;
    int b = blockIdx.x >> 6, o = blockIdx.x & 63;
    int tid = threadIdx.x;
    float* sm = (float*)sh;      // [4]
    float* ss = (float*)sh + 4;  // [4]
    const float* p = out2 + (size_t)b * NN * FOUT + o;
    float v[8];
    float m = -3.4e38f;
#pragma unroll
    for (int j = 0; j < 8; ++j) {
        v[j] = p[(size_t)(tid + 256 * j) * FOUT];
        m = fmaxf(m, v[j]);
    }
    for (int off = 1; off < 64; off <<= 1) m = fmaxf(m, __shfl_xor(m, off));
    if ((tid & 63) == 0) sm[tid >> 6] = m;
    __syncthreads();
    float M = fmaxf(fmaxf(sm[0], sm[1]), fmaxf(sm[2], sm[3]));
    float sum = 0.f;
#pragma unroll
    for (int j = 0; j < 8; ++j) sum += expf(v[j] - M);
    for (int off = 1; off < 64; off <<= 1) sum += __shfl_xor(sum, off);
    if ((tid & 63) == 0) ss[tid >> 6] = sum;
    __syncthreads();
    float lse = M + logf(ss[0] + ss[1] + ss[2] + ss[3]);
    float* op = out + (size_t)b * NN * FOUT + o;
#pragma unroll
    for (int j = 0; j < 8; ++j) op[(size_t)(tid + 256 * j) * FOUT] = v[j] - lse;
}

// ===========================================================================
// Cooperative all-in-one kernel
// ===========================================================================
__global__ __launch_bounds__(TPB, 1)
void k_coop(const float* x, const int* edges, int E,
            const float* Wh, const float* ah, const float* bh,
            const float* Wo, const float* ao, const float* bo,
            float* h1, float* s1h, float* s2h,
            float* h2, float* s1o, float* s2o, float* out2,
            int* cnt, int* csr, float* out)
{
    cg::grid_group grid = cg::this_grid();
    __shared__ __align__(16) char sh[16 * FIN * 4];   // 16 KB, reused per phase
    phase_gemm1(x, Wh, ah, h1, s1h, s2h, cnt, (float (*)[FIN])sh);
    grid.sync();
    phase_scatter(edges, E, cnt, csr);
    grid.sync();
    phase_att1(h1, s1h, s2h, bh, cnt, csr, Wo, ao, h2, s1o, s2o, sh);
    grid.sync();
    phase_att2(h2, s1o, s2o, bo, cnt, csr, out2, sh);
    grid.sync();
    phase_lse(out2, out, sh);
}

// Fallback: same phases as separate dispatches (if coop launch unsupported).
__global__ __launch_bounds__(TPB) void k_s0(const float* x, const float* Wh,
    const float* ah, float* h1, float* s1h, float* s2h, int* cnt)
{ __shared__ __align__(16) char sh[16 * FIN * 4];
  phase_gemm1(x, Wh, ah, h1, s1h, s2h, cnt, (float (*)[FIN])sh); }
__global__ __launch_bounds__(TPB) void k_s1(const int* edges, int E, int* cnt, int* csr)
{ phase_scatter(edges, E, cnt, csr); }
__global__ __launch_bounds__(TPB) void k_s2(const float* h1, const float* s1h,
    const float* s2h, const float* bh, const int* cnt, const int* csr,
    const float* Wo, const float* ao, float* h2, float* s1o, float* s2o)
{ __shared__ __align__(16) char sh[6 * 1024];
  phase_att1(h1, s1h, s2h, bh, cnt, csr, Wo, ao, h2, s1o, s2o, sh); }
__global__ __launch_bounds__(TPB) void k_s3(const float* h2, const float* s1o,
    const float* s2o, const float* bo, const int* cnt, const int* csr, float* out2)
{ __shared__ __align__(16) char sh[6 * 1024];
  phase_att2(h2, s1o, s2o, bo, cnt, csr, out2, sh); }
__global__ __launch_bounds__(TPB) void k_s4(const float* out2, float* out)
{ __shared__ __align__(16) char sh[64];
  phase_lse(out2, out, sh); }

// ===========================================================================
extern "C" void kernel_launch(void* const* d_in, const int* in_sizes, int n_in,
                              void* d_out, int out_size, void* d_ws, size_t ws_size,
                              hipStream_t stream)
{
    (void)n_in; (void)out_size; (void)ws_size;
    const float* x     = (const float*)d_in[0];
    const int*   edges = (const int*)d_in[1];
    const float* Wh    = (const float*)d_in[2];
    const float* ah    = (const float*)d_in[3];
    const float* bh    = (const float*)d_in[4];
    const float* Wo    = (const float*)d_in[5];
    const float* ao    = (const float*)d_in[6];
    const float* bo    = (const float*)d_in[7];
    int E = in_sizes[1] / 2;
    float* out = (float*)d_out;

    char* w = (char*)d_ws;
    float* h1   = (float*)w; w += (size_t)BB * NN * C1 * 4;     // 1 MB
    float* s1h  = (float*)w; w += (size_t)BB * HH * NN * 4;     // 128 KB
    float* s2h  = (float*)w; w += (size_t)BB * HH * NN * 4;     // 128 KB
    float* h2   = (float*)w; w += (size_t)BB * NN * FOUT * 4;   // 1 MB
    float* s1o  = (float*)w; w += (size_t)BB * NN * 4;
    float* s2o  = (float*)w; w += (size_t)BB * NN * 4;
    float* out2 = (float*)w; w += (size_t)BB * NN * FOUT * 4;   // 1 MB
    int*   cnt  = (int*)w;   w += (size_t)NN * 4;
    int*   csr  = (int*)w;   w += (size_t)NN * MAXD * 4;        // 1.5 MB

    void* args[] = { &x, &edges, &E, &Wh, &ah, &bh, &Wo, &ao, &bo,
                     &h1, &s1h, &s2h, &h2, &s1o, &s2o, &out2, &cnt, &csr, &out };
    hipError_t err = hipLaunchCooperativeKernel((void*)k_coop, dim3(NB), dim3(TPB),
                                                args, 0, stream);
    if (err != hipSuccess) {
        // Fallback: same phases, separate dispatches.
        k_s0<<<NB, TPB, 0, stream>>>(x, Wh, ah, h1, s1h, s2h, cnt);
        k_s1<<<NB, TPB, 0, stream>>>(edges, E, cnt, csr);
        k_s2<<<NB, TPB, 0, stream>>>(h1, s1h, s2h, bh, cnt, csr, Wo, ao, h2, s1o, s2o);
        k_s3<<<NB, TPB, 0, stream>>>(h2, s1o, s2o, bo, cnt, csr, out2);
        k_s4<<<NB, TPB, 0, stream>>>(out2, out);
    }
}

// Round 5
// 139.033 us; speedup vs baseline: 2.2663x; 2.2663x over previous
//
#include <hip/hip_runtime.h>

// B=2, N=2048, E=32768, Fin=256, nhead=8, nhid=8 (C1=64), Fout=64. All f32.
#define BB   2
#define NN   2048
#define FIN  256
#define HH   8
#define NHID 8
#define C1   64
#define FOUT 64
#define MAXD 192   // fixed CSR row capacity (Poisson(16) max over 2048 rows ~45)

// ---------------------------------------------------------------------------
// K1: h1 = x @ W_h (+ fused s1/s2). 16 nodes/block, 4 nodes/wave (4x W reuse).
// Also zeroes cnt[] (visible to K2 via kernel boundary).
__global__ __launch_bounds__(256)
void k_gemm1(const float* __restrict__ x, const float* __restrict__ Wh,
             const float* __restrict__ ah,
             float* __restrict__ h1, float* __restrict__ s1h, float* __restrict__ s2h,
             int* __restrict__ cnt)
{
    __shared__ float xs[16][FIN];   // 16 KB
    int tid = threadIdx.x;
    int gtid = blockIdx.x * 256 + tid;
    if (gtid < NN) cnt[gtid] = 0;

    int base = blockIdx.x * 16;
    const float4* xv = (const float4*)(x + (size_t)base * FIN);
    float4* xsv = (float4*)&xs[0][0];
#pragma unroll
    for (int i = 0; i < 4; ++i) xsv[tid + 256 * i] = xv[tid + 256 * i];
    __syncthreads();

    int wave = tid >> 6, lane = tid & 63;
    int head = lane >> 3, k = lane & 7;
    const float* Wp = Wh + head * FIN * NHID + k;
    int n0 = wave * 4;
    float a0 = 0.f, a1 = 0.f, a2 = 0.f, a3 = 0.f;
#pragma unroll 4
    for (int f = 0; f < FIN; ++f) {
        float wv = Wp[f * NHID];
        a0 += wv * xs[n0 + 0][f];
        a1 += wv * xs[n0 + 1][f];
        a2 += wv * xs[n0 + 2][f];
        a3 += wv * xs[n0 + 3][f];
    }
    size_t hb = (size_t)(base + n0) * C1 + lane;
    h1[hb] = a0; h1[hb + C1] = a1; h1[hb + 2 * C1] = a2; h1[hb + 3 * C1] = a3;

    float c1 = ah[head * 16 + k], c2 = ah[head * 16 + 8 + k];
    float p0 = a0 * c1, p1 = a1 * c1, p2 = a2 * c1, p3 = a3 * c1;
    float q0 = a0 * c2, q1 = a1 * c2, q2 = a2 * c2, q3 = a3 * c2;
    for (int o = 1; o < 8; o <<= 1) {
        p0 += __shfl_xor(p0, o); p1 += __shfl_xor(p1, o);
        p2 += __shfl_xor(p2, o); p3 += __shfl_xor(p3, o);
        q0 += __shfl_xor(q0, o); q1 += __shfl_xor(q1, o);
        q2 += __shfl_xor(q2, o); q3 += __shfl_xor(q3, o);
    }
    if (k == 0) {
        float ps[4] = {p0, p1, p2, p3}, qs[4] = {q0, q1, q2, q3};
#pragma unroll
        for (int j = 0; j < 4; ++j) {
            int bn = base + n0 + j;
            int b = bn >> 11, n = bn & (NN - 1);
            s1h[(b * HH + head) * NN + n] = ps[j];
            s2h[(b * HH + head) * NN + n] = qs[j];
        }
    }
}

// ---------------------------------------------------------------------------
// K2: scatter edges into fixed-stride CSR rows (duplicates kept; dedup later).
__global__ __launch_bounds__(256)
void k_scatter(const int* __restrict__ edges, int E,
               int* __restrict__ cnt, int* __restrict__ csr)
{
    int e = blockIdx.x * 256 + threadIdx.x;
    if (e >= E) return;
    int s = edges[e], t = edges[E + e];
    int pos = atomicAdd(&cnt[s], 1);
    if (pos < MAXD) csr[s * MAXD + pos] = t;
}

// ---------------------------------------------------------------------------
// K3: layer-1 sparse attention (dedup: mark later duplicates -1) + elu +
// gemm2 + s1o/s2o. 4 nodes/block, one wave per node, wave-private LDS,
// no __syncthreads (wave-lockstep + compiler lgkmcnt ordering).
__global__ __launch_bounds__(256)
void k_att1g2(const float* __restrict__ h1, const float* __restrict__ s1h,
              const float* __restrict__ s2h, const float* __restrict__ bh,
              const int* __restrict__ cnt, const int* __restrict__ csr,
              const float* __restrict__ Wo, const float* __restrict__ ao,
              float* __restrict__ h2, float* __restrict__ s1o, float* __restrict__ s2o)
{
    __shared__ int tg4[4][MAXD];
    __shared__ float xs4[4][C1];
    int tid = threadIdx.x, w = tid >> 6, lane = tid & 63;
    int* tg = tg4[w];
    float* xs = xs4[w];
    int bn = blockIdx.x * 4 + w;
    int b = bn >> 11, n = bn & (NN - 1);
    int head = lane >> 3;

    int d = cnt[n]; if (d > MAXD) d = MAXD;
    for (int l = lane; l < d; l += 64) tg[l] = csr[n * MAXD + l];
    // dedup: first occurrence kept; later dups -> -1 (first occ never marked,
    // so concurrent in-wave marking cannot hide a match).
    for (int l = lane; l < d; l += 64) {
        int t = tg[l], f = 0;
        for (int j = 0; j < l; ++j) f |= (tg[j] == t);
        if (f) tg[l] = -1;
    }

    const float* hp = h1 + (size_t)b * NN * C1 + lane;
    float out;
    if (d == 0) {   // dense -1e20 row -> uniform softmax over all N
        float acc = 0.f;
        for (int j = 0; j < NN; ++j) acc += hp[(size_t)j * C1];
        out = acc * (1.0f / NN);
    } else {
        float s1 = s1h[(b * HH + head) * NN + n];
        const float* s2p = s2h + (b * HH + head) * NN;
        float m = -3.4e38f;
        for (int p = 0; p < d; ++p) {
            int t = tg[p]; if (t < 0) continue;
            float ee = s1 + s2p[t];
            ee = ee > 0.f ? ee : 0.2f * ee;
            m = fmaxf(m, ee);
        }
        float den = 0.f, acc = 0.f;
        for (int p = 0; p < d; ++p) {
            int t = tg[p]; if (t < 0) continue;
            float ee = s1 + s2p[t];
            ee = ee > 0.f ? ee : 0.2f * ee;
            float wt = expf(ee - m);
            den += wt;
            acc += wt * hp[(size_t)t * C1];
        }
        out = acc / den;
    }
    out += bh[lane];
    xs[lane] = out > 0.f ? out : (expf(out) - 1.f);   // elu

    // gemm2 within the same wave (xs is wave-private)
    float acc2 = 0.f;
#pragma unroll 16
    for (int f = 0; f < C1; ++f) acc2 += xs[f] * Wo[f * FOUT + lane];
    h2[(size_t)bn * FOUT + lane] = acc2;
    float p = acc2 * ao[lane];
    float q = acc2 * ao[FOUT + lane];
    for (int o = 1; o < 64; o <<= 1) { p += __shfl_xor(p, o); q += __shfl_xor(q, o); }
    if (lane == 0) { s1o[bn] = p; s2o[bn] = q; }
}

// ---------------------------------------------------------------------------
// K4: layer-2 sparse attention (same dedup) -> out2 (pre-logsoftmax).
__global__ __launch_bounds__(256)
void k_att2(const float* __restrict__ h2, const float* __restrict__ s1o,
            const float* __restrict__ s2o, const float* __restrict__ bo,
            const int* __restrict__ cnt, const int* __restrict__ csr,
            float* __restrict__ out2)
{
    __shared__ int tg4[4][MAXD];
    int tid = threadIdx.x, w = tid >> 6, lane = tid & 63;
    int* tg = tg4[w];
    int bn = blockIdx.x * 4 + w;
    int b = bn >> 11, n = bn & (NN - 1);

    int d = cnt[n]; if (d > MAXD) d = MAXD;
    for (int l = lane; l < d; l += 64) tg[l] = csr[n * MAXD + l];
    for (int l = lane; l < d; l += 64) {
        int t = tg[l], f = 0;
        for (int j = 0; j < l; ++j) f |= (tg[j] == t);
        if (f) tg[l] = -1;
    }

    const float* hp = h2 + (size_t)b * NN * FOUT + lane;
    float out;
    if (d == 0) {
        float acc = 0.f;
        for (int j = 0; j < NN; ++j) acc += hp[(size_t)j * FOUT];
        out = acc * (1.0f / NN);
    } else {
        float s1 = s1o[bn];
        const float* s2p = s2o + b * NN;
        float m = -3.4e38f;
        for (int p = 0; p < d; ++p) {
            int t = tg[p]; if (t < 0) continue;
            float ee = s1 + s2p[t];
            ee = ee > 0.f ? ee : 0.2f * ee;
            m = fmaxf(m, ee);
        }
        float den = 0.f, acc = 0.f;
        for (int p = 0; p < d; ++p) {
            int t = tg[p]; if (t < 0) continue;
            float ee = s1 + s2p[t];
            ee = ee > 0.f ? ee : 0.2f * ee;
            float wt = expf(ee - m);
            den += wt;
            acc += wt * hp[(size_t)t * FOUT];
        }
        out = acc / den;
    }
    out2[(size_t)bn * FOUT + lane] = out + bo[lane];
}

// ---------------------------------------------------------------------------
// K5: fused logsumexp over node axis + subtract + store. grid = B*FOUT.
__global__ __launch_bounds__(256)
void k_lsef(const float* __restrict__ out2, float* __restrict__ out)
{
    int b = blockIdx.x >> 6, o = blockIdx.x & 63;
    int tid = threadIdx.x;
    const float* p = out2 + (size_t)b * NN * FOUT + o;
    float v[8];
    float m = -3.4e38f;
#pragma unroll
    for (int j = 0; j < 8; ++j) {
        v[j] = p[(size_t)(tid + 256 * j) * FOUT];
        m = fmaxf(m, v[j]);
    }
    for (int off = 1; off < 64; off <<= 1) m = fmaxf(m, __shfl_xor(m, off));
    __shared__ float sm[4], ss[4];
    if ((tid & 63) == 0) sm[tid >> 6] = m;
    __syncthreads();
    float M = fmaxf(fmaxf(sm[0], sm[1]), fmaxf(sm[2], sm[3]));
    float sum = 0.f;
#pragma unroll
    for (int j = 0; j < 8; ++j) sum += expf(v[j] - M);
    for (int off = 1; off < 64; off <<= 1) sum += __shfl_xor(sum, off);
    if ((tid & 63) == 0) ss[tid >> 6] = sum;
    __syncthreads();
    float lse = M + logf(ss[0] + ss[1] + ss[2] + ss[3]);
    float* op = out + (size_t)b * NN * FOUT + o;
#pragma unroll
    for (int j = 0; j < 8; ++j) op[(size_t)(tid + 256 * j) * FOUT] = v[j] - lse;
}

// ---------------------------------------------------------------------------
extern "C" void kernel_launch(void* const* d_in, const int* in_sizes, int n_in,
                              void* d_out, int out_size, void* d_ws, size_t ws_size,
                              hipStream_t stream)
{
    (void)n_in; (void)out_size; (void)ws_size;
    const float* x     = (const float*)d_in[0];
    const int*   edges = (const int*)d_in[1];
    const float* Wh    = (const float*)d_in[2];
    const float* ah    = (const float*)d_in[3];
    const float* bh    = (const float*)d_in[4];
    const float* Wo    = (const float*)d_in[5];
    const float* ao    = (const float*)d_in[6];
    const float* bo    = (const float*)d_in[7];
    int E = in_sizes[1] / 2;

    char* w = (char*)d_ws;
    float* h1   = (float*)w; w += (size_t)BB * NN * C1 * 4;     // 1 MB
    float* s1h  = (float*)w; w += (size_t)BB * HH * NN * 4;     // 128 KB
    float* s2h  = (float*)w; w += (size_t)BB * HH * NN * 4;     // 128 KB
    float* h2   = (float*)w; w += (size_t)BB * NN * FOUT * 4;   // 1 MB
    float* s1o  = (float*)w; w += (size_t)BB * NN * 4;
    float* s2o  = (float*)w; w += (size_t)BB * NN * 4;
    float* out2 = (float*)w; w += (size_t)BB * NN * FOUT * 4;   // 1 MB
    int*   cnt  = (int*)w;   w += (size_t)NN * 4;
    int*   csr  = (int*)w;   w += (size_t)NN * MAXD * 4;        // 1.5 MB

    k_gemm1  <<<BB * NN / 16, 256, 0, stream>>>(x, Wh, ah, h1, s1h, s2h, cnt);
    k_scatter<<<(E + 255) / 256, 256, 0, stream>>>(edges, E, cnt, csr);
    k_att1g2 <<<BB * NN / 4, 256, 0, stream>>>(h1, s1h, s2h, bh, cnt, csr, Wo, ao, h2, s1o, s2o);
    k_att2   <<<BB * NN / 4, 256, 0, stream>>>(h2, s1o, s2o, bo, cnt, csr, out2);
    k_lsef   <<<BB * FOUT, 256, 0, stream>>>(out2, (float*)d_out);
}

// Round 6
// 136.650 us; speedup vs baseline: 2.3058x; 1.0174x over previous
//
#include <hip/hip_runtime.h>

// B=2, N=2048, E=32768, Fin=256, nhead=8, nhid=8 (C1=64), Fout=64. All f32.
#define BB   2
#define NN   2048
#define FIN  256
#define HH   8
#define NHID 8
#define C1   64
#define FOUT 64
#define MAXD 192   // fixed CSR row capacity (Poisson(16) max over 2048 rows ~45)

// ---------------------------------------------------------------------------
// K1 "front": blocks 0..255 = gemm1 (h1 = x @ W_h, fused s1/s2);
//             blocks 256..  = edge scatter into fixed-stride CSR.
// cnt[] is zeroed by a preceding hipMemsetAsync (stream-ordered).
__global__ __launch_bounds__(256)
void k_front(const float* __restrict__ x, const float* __restrict__ Wh,
             const float* __restrict__ ah, const int* __restrict__ edges, int E,
             float* __restrict__ h1, float* __restrict__ s1h, float* __restrict__ s2h,
             int* __restrict__ cnt, int* __restrict__ csr)
{
    __shared__ float xs[16][FIN];   // 16 KB (unused by scatter blocks)
    int tid = threadIdx.x;

    if (blockIdx.x >= 256) {
        // ---- scatter part (independent of gemm part) ----
        int e = (blockIdx.x - 256) * 256 + tid;
        if (e < E) {
            int s = edges[e], t = edges[E + e];
            int pos = atomicAdd(&cnt[s], 1);
            if (pos < MAXD) csr[s * MAXD + pos] = t;
        }
        return;
    }

    // ---- gemm1 part: 16 nodes/block, 4 nodes/wave (4x W reuse) ----
    int base = blockIdx.x * 16;
    const float4* xv = (const float4*)(x + (size_t)base * FIN);
    float4* xsv = (float4*)&xs[0][0];
#pragma unroll
    for (int i = 0; i < 4; ++i) xsv[tid + 256 * i] = xv[tid + 256 * i];
    __syncthreads();

    int wave = tid >> 6, lane = tid & 63;
    int head = lane >> 3, k = lane & 7;
    const float* Wp = Wh + head * FIN * NHID + k;
    int n0 = wave * 4;
    float a0 = 0.f, a1 = 0.f, a2 = 0.f, a3 = 0.f;
#pragma unroll 4
    for (int f = 0; f < FIN; ++f) {
        float wv = Wp[f * NHID];
        a0 += wv * xs[n0 + 0][f];
        a1 += wv * xs[n0 + 1][f];
        a2 += wv * xs[n0 + 2][f];
        a3 += wv * xs[n0 + 3][f];
    }
    size_t hb = (size_t)(base + n0) * C1 + lane;
    h1[hb] = a0; h1[hb + C1] = a1; h1[hb + 2 * C1] = a2; h1[hb + 3 * C1] = a3;

    float c1 = ah[head * 16 + k], c2 = ah[head * 16 + 8 + k];
    float p0 = a0 * c1, p1 = a1 * c1, p2 = a2 * c1, p3 = a3 * c1;
    float q0 = a0 * c2, q1 = a1 * c2, q2 = a2 * c2, q3 = a3 * c2;
    for (int o = 1; o < 8; o <<= 1) {
        p0 += __shfl_xor(p0, o); p1 += __shfl_xor(p1, o);
        p2 += __shfl_xor(p2, o); p3 += __shfl_xor(p3, o);
        q0 += __shfl_xor(q0, o); q1 += __shfl_xor(q1, o);
        q2 += __shfl_xor(q2, o); q3 += __shfl_xor(q3, o);
    }
    if (k == 0) {
        float ps[4] = {p0, p1, p2, p3}, qs[4] = {q0, q1, q2, q3};
#pragma unroll
        for (int j = 0; j < 4; ++j) {
            int bn = base + n0 + j;
            int b = bn >> 11, n = bn & (NN - 1);
            s1h[(b * HH + head) * NN + n] = ps[j];
            s2h[(b * HH + head) * NN + n] = qs[j];
        }
    }
}

// ---------------------------------------------------------------------------
// K2: layer-1 sparse attention (dedup: later duplicates -> -1) + elu +
// gemm2 + s1o/s2o. 4 nodes/block, one wave per node, wave-private LDS,
// no __syncthreads (wave-lockstep + compiler lgkmcnt ordering).
__global__ __launch_bounds__(256)
void k_att1g2(const float* __restrict__ h1, const float* __restrict__ s1h,
              const float* __restrict__ s2h, const float* __restrict__ bh,
              const int* __restrict__ cnt, const int* __restrict__ csr,
              const float* __restrict__ Wo, const float* __restrict__ ao,
              float* __restrict__ h2, float* __restrict__ s1o, float* __restrict__ s2o)
{
    __shared__ int tg4[4][MAXD];
    __shared__ float xs4[4][C1];
    int tid = threadIdx.x, w = tid >> 6, lane = tid & 63;
    int* tg = tg4[w];
    float* xs = xs4[w];
    int bn = blockIdx.x * 4 + w;
    int b = bn >> 11, n = bn & (NN - 1);
    int head = lane >> 3;

    int d = cnt[n]; if (d > MAXD) d = MAXD;
    for (int l = lane; l < d; l += 64) tg[l] = csr[n * MAXD + l];
    for (int l = lane; l < d; l += 64) {
        int t = tg[l], f = 0;
        for (int j = 0; j < l; ++j) f |= (tg[j] == t);
        if (f) tg[l] = -1;
    }

    const float* hp = h1 + (size_t)b * NN * C1 + lane;
    float out;
    if (d == 0) {   // dense -1e20 row -> uniform softmax over all N
        float acc = 0.f;
        for (int j = 0; j < NN; ++j) acc += hp[(size_t)j * C1];
        out = acc * (1.0f / NN);
    } else {
        float s1 = s1h[(b * HH + head) * NN + n];
        const float* s2p = s2h + (b * HH + head) * NN;
        float m = -3.4e38f;
        for (int p = 0; p < d; ++p) {
            int t = tg[p]; if (t < 0) continue;
            float ee = s1 + s2p[t];
            ee = ee > 0.f ? ee : 0.2f * ee;
            m = fmaxf(m, ee);
        }
        float den = 0.f, acc = 0.f;
        for (int p = 0; p < d; ++p) {
            int t = tg[p]; if (t < 0) continue;
            float ee = s1 + s2p[t];
            ee = ee > 0.f ? ee : 0.2f * ee;
            float wt = expf(ee - m);
            den += wt;
            acc += wt * hp[(size_t)t * C1];
        }
        out = acc / den;
    }
    out += bh[lane];
    xs[lane] = out > 0.f ? out : (expf(out) - 1.f);   // elu

    // gemm2 within the same wave (xs is wave-private)
    float acc2 = 0.f;
#pragma unroll 16
    for (int f = 0; f < C1; ++f) acc2 += xs[f] * Wo[f * FOUT + lane];
    h2[(size_t)bn * FOUT + lane] = acc2;
    float p = acc2 * ao[lane];
    float q = acc2 * ao[FOUT + lane];
    for (int o = 1; o < 64; o <<= 1) { p += __shfl_xor(p, o); q += __shfl_xor(q, o); }
    if (lane == 0) { s1o[bn] = p; s2o[bn] = q; }
}

// ---------------------------------------------------------------------------
// K3: layer-2 sparse attention -> TRANSPOSED out2T[b*FOUT+o][n] (for coalesced lse).
__global__ __launch_bounds__(256)
void k_att2(const float* __restrict__ h2, const float* __restrict__ s1o,
            const float* __restrict__ s2o, const float* __restrict__ bo,
            const int* __restrict__ cnt, const int* __restrict__ csr,
            float* __restrict__ out2T)
{
    __shared__ int tg4[4][MAXD];
    int tid = threadIdx.x, w = tid >> 6, lane = tid & 63;
    int* tg = tg4[w];
    int bn = blockIdx.x * 4 + w;
    int b = bn >> 11, n = bn & (NN - 1);

    int d = cnt[n]; if (d > MAXD) d = MAXD;
    for (int l = lane; l < d; l += 64) tg[l] = csr[n * MAXD + l];
    for (int l = lane; l < d; l += 64) {
        int t = tg[l], f = 0;
        for (int j = 0; j < l; ++j) f |= (tg[j] == t);
        if (f) tg[l] = -1;
    }

    const float* hp = h2 + (size_t)b * NN * FOUT + lane;
    float out;
    if (d == 0) {
        float acc = 0.f;
        for (int j = 0; j < NN; ++j) acc += hp[(size_t)j * FOUT];
        out = acc * (1.0f / NN);
    } else {
        float s1 = s1o[bn];
        const float* s2p = s2o + b * NN;
        float m = -3.4e38f;
        for (int p = 0; p < d; ++p) {
            int t = tg[p]; if (t < 0) continue;
            float ee = s1 + s2p[t];
            ee = ee > 0.f ? ee : 0.2f * ee;
            m = fmaxf(m, ee);
        }
        float den = 0.f, acc = 0.f;
        for (int p = 0; p < d; ++p) {
            int t = tg[p]; if (t < 0) continue;
            float ee = s1 + s2p[t];
            ee = ee > 0.f ? ee : 0.2f * ee;
            float wt = expf(ee - m);
            den += wt;
            acc += wt * hp[(size_t)t * FOUT];
        }
        out = acc / den;
    }
    out2T[(size_t)(b * FOUT + lane) * NN + n] = out + bo[lane];
}

// ---------------------------------------------------------------------------
// K4: fused logsumexp over node axis + subtract + store. grid = B*FOUT = 128.
// Reads out2T row (contiguous, coalesced); writes out[b][n][o] (strided, fire-and-forget).
__global__ __launch_bounds__(256)
void k_lsef(const float* __restrict__ out2T, float* __restrict__ out)
{
    int row = blockIdx.x;               // = b*FOUT + o
    int b = row >> 6, o = row & 63;
    int tid = threadIdx.x;
    const float* p = out2T + (size_t)row * NN;
    float v[8];
    float m = -3.4e38f;
#pragma unroll
    for (int j = 0; j < 8; ++j) {
        v[j] = p[tid + 256 * j];
        m = fmaxf(m, v[j]);
    }
    for (int off = 1; off < 64; off <<= 1) m = fmaxf(m, __shfl_xor(m, off));
    __shared__ float sm[4], ss[4];
    if ((tid & 63) == 0) sm[tid >> 6] = m;
    __syncthreads();
    float M = fmaxf(fmaxf(sm[0], sm[1]), fmaxf(sm[2], sm[3]));
    float sum = 0.f;
#pragma unroll
    for (int j = 0; j < 8; ++j) sum += expf(v[j] - M);
    for (int off = 1; off < 64; off <<= 1) sum += __shfl_xor(sum, off);
    if ((tid & 63) == 0) ss[tid >> 6] = sum;
    __syncthreads();
    float lse = M + logf(ss[0] + ss[1] + ss[2] + ss[3]);
    float* op = out + (size_t)b * NN * FOUT + o;
#pragma unroll
    for (int j = 0; j < 8; ++j) op[(size_t)(tid + 256 * j) * FOUT] = v[j] - lse;
}

// ---------------------------------------------------------------------------
extern "C" void kernel_launch(void* const* d_in, const int* in_sizes, int n_in,
                              void* d_out, int out_size, void* d_ws, size_t ws_size,
                              hipStream_t stream)
{
    (void)n_in; (void)out_size; (void)ws_size;
    const float* x     = (const float*)d_in[0];
    const int*   edges = (const int*)d_in[1];
    const float* Wh    = (const float*)d_in[2];
    const float* ah    = (const float*)d_in[3];
    const float* bh    = (const float*)d_in[4];
    const float* Wo    = (const float*)d_in[5];
    const float* ao    = (const float*)d_in[6];
    const float* bo    = (const float*)d_in[7];
    int E = in_sizes[1] / 2;

    char* w = (char*)d_ws;
    float* h1    = (float*)w; w += (size_t)BB * NN * C1 * 4;     // 1 MB
    float* s1h   = (float*)w; w += (size_t)BB * HH * NN * 4;     // 128 KB
    float* s2h   = (float*)w; w += (size_t)BB * HH * NN * 4;     // 128 KB
    float* h2    = (float*)w; w += (size_t)BB * NN * FOUT * 4;   // 1 MB
    float* s1o   = (float*)w; w += (size_t)BB * NN * 4;
    float* s2o   = (float*)w; w += (size_t)BB * NN * 4;
    float* out2T = (float*)w; w += (size_t)BB * FOUT * NN * 4;   // 1 MB
    int*   cnt   = (int*)w;   w += (size_t)NN * 4;
    int*   csr   = (int*)w;   w += (size_t)NN * MAXD * 4;        // 1.5 MB

    hipMemsetAsync(cnt, 0, (size_t)NN * 4, stream);

    int scatter_blocks = (E + 255) / 256;   // 128
    k_front <<<256 + scatter_blocks, 256, 0, stream>>>(x, Wh, ah, edges, E,
                                                       h1, s1h, s2h, cnt, csr);
    k_att1g2<<<BB * NN / 4, 256, 0, stream>>>(h1, s1h, s2h, bh, cnt, csr,
                                              Wo, ao, h2, s1o, s2o);
    k_att2  <<<BB * NN / 4, 256, 0, stream>>>(h2, s1o, s2o, bo, cnt, csr, out2T);
    k_lsef  <<<BB * FOUT, 256, 0, stream>>>(out2T, (float*)d_out);
}

// Round 7
// 113.731 us; speedup vs baseline: 2.7705x; 1.2015x over previous
//
#include <hip/hip_runtime.h>

// B=2, N=2048, E=32768, Fin=256, nhead=8, nhid=8 (C1=64), Fout=64. All f32.
#define BB   2
#define NN   2048
#define FIN  256
#define HH   8
#define NHID 8
#define C1   64
#define FOUT 64
#define MAXD 192   // fixed CSR row capacity (abs cap; Poisson(16) max ~45)
#define FASTD 64   // fast-path cap for LDS score prefetch

// ---------------------------------------------------------------------------
// K1 "front": blocks 0..255 = gemm1 (h1 = x @ W_h, fused s1/s2);
//             blocks 256..  = edge scatter into fixed-stride CSR.
// cnt[] is zeroed by a preceding hipMemsetAsync (stream-ordered).
__global__ __launch_bounds__(256)
void k_front(const float* __restrict__ x, const float* __restrict__ Wh,
             const float* __restrict__ ah, const int* __restrict__ edges, int E,
             float* __restrict__ h1, float* __restrict__ s1h, float* __restrict__ s2h,
             int* __restrict__ cnt, int* __restrict__ csr)
{
    __shared__ float xs[16][FIN];   // 16 KB (unused by scatter blocks)
    int tid = threadIdx.x;

    if (blockIdx.x >= 256) {
        int e = (blockIdx.x - 256) * 256 + tid;
        if (e < E) {
            int s = edges[e], t = edges[E + e];
            int pos = atomicAdd(&cnt[s], 1);
            if (pos < MAXD) csr[s * MAXD + pos] = t;
        }
        return;
    }

    // ---- gemm1: 16 nodes/block, 4 nodes/wave (4x W reuse) ----
    int base = blockIdx.x * 16;
    const float4* xv = (const float4*)(x + (size_t)base * FIN);
    float4* xsv = (float4*)&xs[0][0];
#pragma unroll
    for (int i = 0; i < 4; ++i) xsv[tid + 256 * i] = xv[tid + 256 * i];
    __syncthreads();

    int wave = tid >> 6, lane = tid & 63;
    int head = lane >> 3, k = lane & 7;
    const float* Wp = Wh + head * FIN * NHID + k;
    int n0 = wave * 4;
    const float4* xr0 = (const float4*)xs[n0 + 0];
    const float4* xr1 = (const float4*)xs[n0 + 1];
    const float4* xr2 = (const float4*)xs[n0 + 2];
    const float4* xr3 = (const float4*)xs[n0 + 3];
    float a0 = 0.f, a1 = 0.f, a2 = 0.f, a3 = 0.f;
#pragma unroll 8
    for (int ff = 0; ff < FIN / 4; ++ff) {
        float4 v0 = xr0[ff], v1 = xr1[ff], v2 = xr2[ff], v3 = xr3[ff];
        float w0 = Wp[(4 * ff + 0) * NHID];
        float w1 = Wp[(4 * ff + 1) * NHID];
        float w2 = Wp[(4 * ff + 2) * NHID];
        float w3 = Wp[(4 * ff + 3) * NHID];
        a0 += w0 * v0.x; a0 += w1 * v0.y; a0 += w2 * v0.z; a0 += w3 * v0.w;
        a1 += w0 * v1.x; a1 += w1 * v1.y; a1 += w2 * v1.z; a1 += w3 * v1.w;
        a2 += w0 * v2.x; a2 += w1 * v2.y; a2 += w2 * v2.z; a2 += w3 * v2.w;
        a3 += w0 * v3.x; a3 += w1 * v3.y; a3 += w2 * v3.z; a3 += w3 * v3.w;
    }
    size_t hb = (size_t)(base + n0) * C1 + lane;
    h1[hb] = a0; h1[hb + C1] = a1; h1[hb + 2 * C1] = a2; h1[hb + 3 * C1] = a3;

    float c1 = ah[head * 16 + k], c2 = ah[head * 16 + 8 + k];
    float p0 = a0 * c1, p1 = a1 * c1, p2 = a2 * c1, p3 = a3 * c1;
    float q0 = a0 * c2, q1 = a1 * c2, q2 = a2 * c2, q3 = a3 * c2;
    for (int o = 1; o < 8; o <<= 1) {
        p0 += __shfl_xor(p0, o); p1 += __shfl_xor(p1, o);
        p2 += __shfl_xor(p2, o); p3 += __shfl_xor(p3, o);
        q0 += __shfl_xor(q0, o); q1 += __shfl_xor(q1, o);
        q2 += __shfl_xor(q2, o); q3 += __shfl_xor(q3, o);
    }
    if (k == 0) {
        float ps[4] = {p0, p1, p2, p3}, qs[4] = {q0, q1, q2, q3};
#pragma unroll
        for (int j = 0; j < 4; ++j) {
            int bn = base + n0 + j;
            int b = bn >> 11, n = bn & (NN - 1);
            s1h[(b * HH + head) * NN + n] = ps[j];
            s2h[(b * HH + head) * NN + n] = qs[j];
        }
    }
}

// ---------------------------------------------------------------------------
// K2: layer-1 sparse attention + elu + gemm2 + s1o/s2o. 4 nodes/block,
// one wave per node, wave-private LDS, no __syncthreads.
// Dedup marks later duplicates -1 and WRITES BACK to csr (att2 skips dedup).
// Fast path (d<=64): per-edge scores prefetched into LDS; hp gathers chunked x4.
__global__ __launch_bounds__(256)
void k_att1g2(const float* __restrict__ h1, const float* __restrict__ s1h,
              const float* __restrict__ s2h, const float* __restrict__ bh,
              const int* __restrict__ cnt, int* __restrict__ csr,
              const float* __restrict__ Wo, const float* __restrict__ ao,
              float* __restrict__ h2, float* __restrict__ s1o, float* __restrict__ s2o)
{
    __shared__ int tg4[4][MAXD];
    __shared__ float es4[4][FASTD][HH];   // 8 KB
    __shared__ float xs4[4][C1];
    int tid = threadIdx.x, w = tid >> 6, lane = tid & 63;
    int* tg = tg4[w];
    float* xs = xs4[w];
    int bn = blockIdx.x * 4 + w;
    int b = bn >> 11, n = bn & (NN - 1);
    int head = lane >> 3;

    int d = cnt[n]; if (d > MAXD) d = MAXD;
    for (int l = lane; l < d; l += 64) tg[l] = csr[n * MAXD + l];
    // dedup: first occurrence kept; later dups -> -1
    for (int l = lane; l < d; l += 64) {
        int t = tg[l], f = 0;
        for (int j = 0; j < l; ++j) f |= (tg[j] == t);
        if (f) tg[l] = -1;
    }
    // write back deduped row so att2 can skip its dedup pass
    for (int l = lane; l < d; l += 64) csr[n * MAXD + l] = tg[l];

    const float* hp = h1 + (size_t)b * NN * C1 + lane;
    float out;
    if (d == 0) {   // dense -1e20 row -> uniform softmax over all N
        float acc = 0.f;
        for (int j = 0; j < NN; ++j) acc += hp[(size_t)j * C1];
        out = acc * (1.0f / NN);
    } else if (d <= FASTD) {
        // prefetch s2 scores for all (edge, head) pairs in parallel
        const float* s2b = s2h + (size_t)b * HH * NN;
        for (int idx = lane; idx < d * HH; idx += 64) {
            int l = idx >> 3, hh = idx & 7;
            int t = tg[l];
            es4[w][l][hh] = s2b[hh * NN + (t < 0 ? 0 : t)];
        }
        float s1 = s1h[(b * HH + head) * NN + n];
        float m = -3.4e38f;
        for (int p = 0; p < d; ++p) {
            float ee = s1 + es4[w][p][head];
            ee = ee > 0.f ? ee : 0.2f * ee;
            m = fmaxf(m, tg[p] < 0 ? -3.4e38f : ee);
        }
        float den = 0.f, acc = 0.f;
        int p = 0;
        for (; p + 4 <= d; p += 4) {
            int t0 = tg[p], t1 = tg[p + 1], t2 = tg[p + 2], t3 = tg[p + 3];
            float v0 = hp[(size_t)(t0 < 0 ? 0 : t0) * C1];
            float v1 = hp[(size_t)(t1 < 0 ? 0 : t1) * C1];
            float v2 = hp[(size_t)(t2 < 0 ? 0 : t2) * C1];
            float v3 = hp[(size_t)(t3 < 0 ? 0 : t3) * C1];
            float e0 = s1 + es4[w][p + 0][head]; e0 = e0 > 0.f ? e0 : 0.2f * e0;
            float e1 = s1 + es4[w][p + 1][head]; e1 = e1 > 0.f ? e1 : 0.2f * e1;
            float e2 = s1 + es4[w][p + 2][head]; e2 = e2 > 0.f ? e2 : 0.2f * e2;
            float e3 = s1 + es4[w][p + 3][head]; e3 = e3 > 0.f ? e3 : 0.2f * e3;
            float w0 = t0 < 0 ? 0.f : expf(e0 - m);
            float w1 = t1 < 0 ? 0.f : expf(e1 - m);
            float w2 = t2 < 0 ? 0.f : expf(e2 - m);
            float w3 = t3 < 0 ? 0.f : expf(e3 - m);
            den += w0; acc += w0 * v0;
            den += w1; acc += w1 * v1;
            den += w2; acc += w2 * v2;
            den += w3; acc += w3 * v3;
        }
        for (; p < d; ++p) {
            int t = tg[p];
            float v = hp[(size_t)(t < 0 ? 0 : t) * C1];
            float ee = s1 + es4[w][p][head];
            ee = ee > 0.f ? ee : 0.2f * ee;
            float wt = t < 0 ? 0.f : expf(ee - m);
            den += wt; acc += wt * v;
        }
        out = acc / den;
    } else {
        // slow fallback (statistically unreachable)
        float s1 = s1h[(b * HH + head) * NN + n];
        const float* s2p = s2h + (b * HH + head) * NN;
        float m = -3.4e38f;
        for (int p = 0; p < d; ++p) {
            int t = tg[p]; if (t < 0) continue;
            float ee = s1 + s2p[t];
            ee = ee > 0.f ? ee : 0.2f * ee;
            m = fmaxf(m, ee);
        }
        float den = 0.f, acc = 0.f;
        for (int p = 0; p < d; ++p) {
            int t = tg[p]; if (t < 0) continue;
            float ee = s1 + s2p[t];
            ee = ee > 0.f ? ee : 0.2f * ee;
            float wt = expf(ee - m);
            den += wt;
            acc += wt * hp[(size_t)t * C1];
        }
        out = acc / den;
    }
    out += bh[lane];
    xs[lane] = out > 0.f ? out : (expf(out) - 1.f);   // elu

    // gemm2 within the same wave (xs is wave-private)
    float acc2 = 0.f;
#pragma unroll 16
    for (int f = 0; f < C1; ++f) acc2 += xs[f] * Wo[f * FOUT + lane];
    h2[(size_t)bn * FOUT + lane] = acc2;
    float p = acc2 * ao[lane];
    float q = acc2 * ao[FOUT + lane];
    for (int o = 1; o < 64; o <<= 1) { p += __shfl_xor(p, o); q += __shfl_xor(q, o); }
    if (lane == 0) { s1o[bn] = p; s2o[bn] = q; }
}

// ---------------------------------------------------------------------------
// K3: layer-2 sparse attention -> TRANSPOSED out2T[b*FOUT+o][n].
// csr already deduped by K2 (-1 entries).
__global__ __launch_bounds__(256)
void k_att2(const float* __restrict__ h2, const float* __restrict__ s1o,
            const float* __restrict__ s2o, const float* __restrict__ bo,
            const int* __restrict__ cnt, const int* __restrict__ csr,
            float* __restrict__ out2T)
{
    __shared__ int tg4[4][MAXD];
    __shared__ float es4[4][FASTD];
    int tid = threadIdx.x, w = tid >> 6, lane = tid & 63;
    int* tg = tg4[w];
    int bn = blockIdx.x * 4 + w;
    int b = bn >> 11, n = bn & (NN - 1);

    int d = cnt[n]; if (d > MAXD) d = MAXD;
    for (int l = lane; l < d; l += 64) tg[l] = csr[n * MAXD + l];

    const float* hp = h2 + (size_t)b * NN * FOUT + lane;
    const float* s2p = s2o + b * NN;
    float out;
    if (d == 0) {
        float acc = 0.f;
        for (int j = 0; j < NN; ++j) acc += hp[(size_t)j * FOUT];
        out = acc * (1.0f / NN);
    } else if (d <= FASTD) {
        for (int l = lane; l < d; l += 64) {
            int t = tg[l];
            es4[w][l] = s2p[t < 0 ? 0 : t];
        }
        float s1 = s1o[bn];
        float m = -3.4e38f;
        for (int p = 0; p < d; ++p) {
            float ee = s1 + es4[w][p];
            ee = ee > 0.f ? ee : 0.2f * ee;
            m = fmaxf(m, tg[p] < 0 ? -3.4e38f : ee);
        }
        float den = 0.f, acc = 0.f;
        int p = 0;
        for (; p + 4 <= d; p += 4) {
            int t0 = tg[p], t1 = tg[p + 1], t2 = tg[p + 2], t3 = tg[p + 3];
            float v0 = hp[(size_t)(t0 < 0 ? 0 : t0) * FOUT];
            float v1 = hp[(size_t)(t1 < 0 ? 0 : t1) * FOUT];
            float v2 = hp[(size_t)(t2 < 0 ? 0 : t2) * FOUT];
            float v3 = hp[(size_t)(t3 < 0 ? 0 : t3) * FOUT];
            float e0 = s1 + es4[w][p + 0]; e0 = e0 > 0.f ? e0 : 0.2f * e0;
            float e1 = s1 + es4[w][p + 1]; e1 = e1 > 0.f ? e1 : 0.2f * e1;
            float e2 = s1 + es4[w][p + 2]; e2 = e2 > 0.f ? e2 : 0.2f * e2;
            float e3 = s1 + es4[w][p + 3]; e3 = e3 > 0.f ? e3 : 0.2f * e3;
            float w0 = t0 < 0 ? 0.f : expf(e0 - m);
            float w1 = t1 < 0 ? 0.f : expf(e1 - m);
            float w2 = t2 < 0 ? 0.f : expf(e2 - m);
            float w3 = t3 < 0 ? 0.f : expf(e3 - m);
            den += w0; acc += w0 * v0;
            den += w1; acc += w1 * v1;
            den += w2; acc += w2 * v2;
            den += w3; acc += w3 * v3;
        }
        for (; p < d; ++p) {
            int t = tg[p];
            float v = hp[(size_t)(t < 0 ? 0 : t) * FOUT];
            float ee = s1 + es4[w][p];
            ee = ee > 0.f ? ee : 0.2f * ee;
            float wt = t < 0 ? 0.f : expf(ee - m);
            den += wt; acc += wt * v;
        }
        out = acc / den;
    } else {
        float s1 = s1o[bn];
        float m = -3.4e38f;
        for (int p = 0; p < d; ++p) {
            int t = tg[p]; if (t < 0) continue;
            float ee = s1 + s2p[t];
            ee = ee > 0.f ? ee : 0.2f * ee;
            m = fmaxf(m, ee);
        }
        float den = 0.f, acc = 0.f;
        for (int p = 0; p < d; ++p) {
            int t = tg[p]; if (t < 0) continue;
            float ee = s1 + s2p[t];
            ee = ee > 0.f ? ee : 0.2f * ee;
            float wt = expf(ee - m);
            den += wt;
            acc += wt * hp[(size_t)t * FOUT];
        }
        out = acc / den;
    }
    out2T[(size_t)(b * FOUT + lane) * NN + n] = out + bo[lane];
}

// ---------------------------------------------------------------------------
// K4: fused logsumexp over node axis + subtract + store. grid = B*FOUT = 128.
__global__ __launch_bounds__(256)
void k_lsef(const float* __restrict__ out2T, float* __restrict__ out)
{
    int row = blockIdx.x;               // = b*FOUT + o
    int b = row >> 6, o = row & 63;
    int tid = threadIdx.x;
    const float* p = out2T + (size_t)row * NN;
    float v[8];
    float m = -3.4e38f;
#pragma unroll
    for (int j = 0; j < 8; ++j) {
        v[j] = p[tid + 256 * j];
        m = fmaxf(m, v[j]);
    }
    for (int off = 1; off < 64; off <<= 1) m = fmaxf(m, __shfl_xor(m, off));
    __shared__ float sm[4], ss[4];
    if ((tid & 63) == 0) sm[tid >> 6] = m;
    __syncthreads();
    float M = fmaxf(fmaxf(sm[0], sm[1]), fmaxf(sm[2], sm[3]));
    float sum = 0.f;
#pragma unroll
    for (int j = 0; j < 8; ++j) sum += expf(v[j] - M);
    for (int off = 1; off < 64; off <<= 1) sum += __shfl_xor(sum, off);
    if ((tid & 63) == 0) ss[tid >> 6] = sum;
    __syncthreads();
    float lse = M + logf(ss[0] + ss[1] + ss[2] + ss[3]);
    float* op = out + (size_t)b * NN * FOUT + o;
#pragma unroll
    for (int j = 0; j < 8; ++j) op[(size_t)(tid + 256 * j) * FOUT] = v[j] - lse;
}

// ---------------------------------------------------------------------------
extern "C" void kernel_launch(void* const* d_in, const int* in_sizes, int n_in,
                              void* d_out, int out_size, void* d_ws, size_t ws_size,
                              hipStream_t stream)
{
    (void)n_in; (void)out_size; (void)ws_size;
    const float* x     = (const float*)d_in[0];
    const int*   edges = (const int*)d_in[1];
    const float* Wh    = (const float*)d_in[2];
    const float* ah    = (const float*)d_in[3];
    const float* bh    = (const float*)d_in[4];
    const float* Wo    = (const float*)d_in[5];
    const float* ao    = (const float*)d_in[6];
    const float* bo    = (const float*)d_in[7];
    int E = in_sizes[1] / 2;

    char* w = (char*)d_ws;
    float* h1    = (float*)w; w += (size_t)BB * NN * C1 * 4;     // 1 MB
    float* s1h   = (float*)w; w += (size_t)BB * HH * NN * 4;     // 128 KB
    float* s2h   = (float*)w; w += (size_t)BB * HH * NN * 4;     // 128 KB
    float* h2    = (float*)w; w += (size_t)BB * NN * FOUT * 4;   // 1 MB
    float* s1o   = (float*)w; w += (size_t)BB * NN * 4;
    float* s2o   = (float*)w; w += (size_t)BB * NN * 4;
    float* out2T = (float*)w; w += (size_t)BB * FOUT * NN * 4;   // 1 MB
    int*   cnt   = (int*)w;   w += (size_t)NN * 4;
    int*   csr   = (int*)w;   w += (size_t)NN * MAXD * 4;        // 1.5 MB

    hipMemsetAsync(cnt, 0, (size_t)NN * 4, stream);

    int scatter_blocks = (E + 255) / 256;   // 128
    k_front <<<256 + scatter_blocks, 256, 0, stream>>>(x, Wh, ah, edges, E,
                                                       h1, s1h, s2h, cnt, csr);
    k_att1g2<<<BB * NN / 4, 256, 0, stream>>>(h1, s1h, s2h, bh, cnt, csr,
                                              Wo, ao, h2, s1o, s2o);
    k_att2  <<<BB * NN / 4, 256, 0, stream>>>(h2, s1o, s2o, bo, cnt, csr, out2T);
    k_lsef  <<<BB * FOUT, 256, 0, stream>>>(out2T, (float*)d_out);
}

// Round 8
// 111.433 us; speedup vs baseline: 2.8276x; 1.0206x over previous
//
#include <hip/hip_runtime.h>

// B=2, N=2048, E=32768, Fin=256, nhead=8, nhid=8 (C1=64), Fout=64. All f32.
#define BB   2
#define NN   2048
#define FIN  256
#define HH   8
#define NHID 8
#define C1   64
#define FOUT 64
#define MAXD 192   // fixed CSR row capacity (abs cap; Poisson(16) max ~45)
#define FASTD 64   // fast-path cap for LDS score prefetch
#define GB1  512   // gemm1 blocks (8 nodes each)

// ---------------------------------------------------------------------------
// K1 "front": blocks 0..GB1-1 = gemm1 (h1 = x @ W_h, fused s1/s2, 8 nodes/blk,
//             2 nodes/wave); blocks GB1.. = edge scatter into fixed-stride CSR.
// cnt[] is zeroed by a preceding hipMemsetAsync (stream-ordered).
// Score layout: s1h/s2h[b][n][head] (head-contiguous for coalesced prefetch).
__global__ __launch_bounds__(256)
void k_front(const float* __restrict__ x, const float* __restrict__ Wh,
             const float* __restrict__ ah, const int* __restrict__ edges, int E,
             float* __restrict__ h1, float* __restrict__ s1h, float* __restrict__ s2h,
             int* __restrict__ cnt, int* __restrict__ csr)
{
    __shared__ float xs[8][FIN];   // 8 KB (unused by scatter blocks)
    int tid = threadIdx.x;

    if (blockIdx.x >= GB1) {
        int e = (blockIdx.x - GB1) * 256 + tid;
        if (e < E) {
            int s = edges[e], t = edges[E + e];
            int pos = atomicAdd(&cnt[s], 1);
            if (pos < MAXD) csr[s * MAXD + pos] = t;
        }
        return;
    }

    // ---- gemm1: 8 nodes/block, 2 nodes/wave ----
    int base = blockIdx.x * 8;
    const float4* xv = (const float4*)(x + (size_t)base * FIN);
    float4* xsv = (float4*)&xs[0][0];
    xsv[tid] = xv[tid];
    xsv[tid + 256] = xv[tid + 256];
    __syncthreads();

    int wave = tid >> 6, lane = tid & 63;
    int head = lane >> 3, k = lane & 7;
    const float* Wp = Wh + head * FIN * NHID + k;
    int n0 = wave * 2;
    const float4* xr0 = (const float4*)xs[n0 + 0];
    const float4* xr1 = (const float4*)xs[n0 + 1];
    float a0 = 0.f, a1 = 0.f;
#pragma unroll 8
    for (int ff = 0; ff < FIN / 4; ++ff) {
        float4 v0 = xr0[ff], v1 = xr1[ff];
        float w0 = Wp[(4 * ff + 0) * NHID];
        float w1 = Wp[(4 * ff + 1) * NHID];
        float w2 = Wp[(4 * ff + 2) * NHID];
        float w3 = Wp[(4 * ff + 3) * NHID];
        a0 += w0 * v0.x; a0 += w1 * v0.y; a0 += w2 * v0.z; a0 += w3 * v0.w;
        a1 += w0 * v1.x; a1 += w1 * v1.y; a1 += w2 * v1.z; a1 += w3 * v1.w;
    }
    size_t hb = (size_t)(base + n0) * C1 + lane;
    h1[hb] = a0; h1[hb + C1] = a1;

    float c1 = ah[head * 16 + k], c2 = ah[head * 16 + 8 + k];
    float p0 = a0 * c1, p1 = a1 * c1;
    float q0 = a0 * c2, q1 = a1 * c2;
    for (int o = 1; o < 8; o <<= 1) {
        p0 += __shfl_xor(p0, o); p1 += __shfl_xor(p1, o);
        q0 += __shfl_xor(q0, o); q1 += __shfl_xor(q1, o);
    }
    if (k == 0) {
        float ps[2] = {p0, p1}, qs[2] = {q0, q1};
#pragma unroll
        for (int j = 0; j < 2; ++j) {
            int bn = base + n0 + j;
            s1h[(size_t)bn * HH + head] = ps[j];
            s2h[(size_t)bn * HH + head] = qs[j];
        }
    }
}

// ---------------------------------------------------------------------------
// K2: layer-1 sparse attention + elu + gemm2 + s1o/s2o. 4 nodes/block,
// one wave per node, wave-private LDS, no __syncthreads.
// Dedup marks later duplicates -1 and WRITES BACK to csr (att2 skips dedup).
__global__ __launch_bounds__(256)
void k_att1g2(const float* __restrict__ h1, const float* __restrict__ s1h,
              const float* __restrict__ s2h, const float* __restrict__ bh,
              const int* __restrict__ cnt, int* __restrict__ csr,
              const float* __restrict__ Wo, const float* __restrict__ ao,
              float* __restrict__ h2, float* __restrict__ s1o, float* __restrict__ s2o)
{
    __shared__ int tg4[4][MAXD];
    __shared__ float es4[4][FASTD][HH];   // 8 KB
    __shared__ float xs4[4][C1];
    int tid = threadIdx.x, w = tid >> 6, lane = tid & 63;
    int* tg = tg4[w];
    float* xs = xs4[w];
    int bn = blockIdx.x * 4 + w;
    int b = bn >> 11, n = bn & (NN - 1);
    int head = lane >> 3;

    int d = cnt[n]; if (d > MAXD) d = MAXD;
    for (int l = lane; l < d; l += 64) tg[l] = csr[n * MAXD + l];
    // dedup: first occurrence kept; later dups -> -1
    for (int l = lane; l < d; l += 64) {
        int t = tg[l], f = 0;
        for (int j = 0; j < l; ++j) f |= (tg[j] == t);
        if (f) tg[l] = -1;
    }
    // write back deduped row so att2 can skip its dedup pass
    for (int l = lane; l < d; l += 64) csr[n * MAXD + l] = tg[l];

    const float* hp = h1 + (size_t)b * NN * C1 + lane;
    float out;
    if (d == 0) {   // dense -1e20 row -> uniform softmax over all N
        float acc = 0.f;
        for (int j = 0; j < NN; ++j) acc += hp[(size_t)j * C1];
        out = acc * (1.0f / NN);
    } else if (d <= FASTD) {
        // prefetch s2 scores: contiguous 8 floats per edge (coalesced)
        const float* s2b = s2h + (size_t)b * NN * HH;
        for (int idx = lane; idx < d * HH; idx += 64) {
            int l = idx >> 3, hh = idx & 7;
            int t = tg[l];
            es4[w][l][hh] = s2b[(size_t)(t < 0 ? 0 : t) * HH + hh];
        }
        float s1 = s1h[(size_t)bn * HH + head];
        float m = -3.4e38f;
        for (int p = 0; p < d; ++p) {
            float ee = s1 + es4[w][p][head];
            ee = ee > 0.f ? ee : 0.2f * ee;
            m = fmaxf(m, tg[p] < 0 ? -3.4e38f : ee);
        }
        float den = 0.f, acc = 0.f;
        int p = 0;
        for (; p + 4 <= d; p += 4) {
            int t0 = tg[p], t1 = tg[p + 1], t2 = tg[p + 2], t3 = tg[p + 3];
            float v0 = hp[(size_t)(t0 < 0 ? 0 : t0) * C1];
            float v1 = hp[(size_t)(t1 < 0 ? 0 : t1) * C1];
            float v2 = hp[(size_t)(t2 < 0 ? 0 : t2) * C1];
            float v3 = hp[(size_t)(t3 < 0 ? 0 : t3) * C1];
            float e0 = s1 + es4[w][p + 0][head]; e0 = e0 > 0.f ? e0 : 0.2f * e0;
            float e1 = s1 + es4[w][p + 1][head]; e1 = e1 > 0.f ? e1 : 0.2f * e1;
            float e2 = s1 + es4[w][p + 2][head]; e2 = e2 > 0.f ? e2 : 0.2f * e2;
            float e3 = s1 + es4[w][p + 3][head]; e3 = e3 > 0.f ? e3 : 0.2f * e3;
            float w0 = t0 < 0 ? 0.f : expf(e0 - m);
            float w1 = t1 < 0 ? 0.f : expf(e1 - m);
            float w2 = t2 < 0 ? 0.f : expf(e2 - m);
            float w3 = t3 < 0 ? 0.f : expf(e3 - m);
            den += w0; acc += w0 * v0;
            den += w1; acc += w1 * v1;
            den += w2; acc += w2 * v2;
            den += w3; acc += w3 * v3;
        }
        for (; p < d; ++p) {
            int t = tg[p];
            float v = hp[(size_t)(t < 0 ? 0 : t) * C1];
            float ee = s1 + es4[w][p][head];
            ee = ee > 0.f ? ee : 0.2f * ee;
            float wt = t < 0 ? 0.f : expf(ee - m);
            den += wt; acc += wt * v;
        }
        out = acc / den;
    } else {
        // slow fallback (statistically unreachable)
        float s1 = s1h[(size_t)bn * HH + head];
        const float* s2b = s2h + (size_t)b * NN * HH;
        float m = -3.4e38f;
        for (int p = 0; p < d; ++p) {
            int t = tg[p]; if (t < 0) continue;
            float ee = s1 + s2b[(size_t)t * HH + head];
            ee = ee > 0.f ? ee : 0.2f * ee;
            m = fmaxf(m, ee);
        }
        float den = 0.f, acc = 0.f;
        for (int p = 0; p < d; ++p) {
            int t = tg[p]; if (t < 0) continue;
            float ee = s1 + s2b[(size_t)t * HH + head];
            ee = ee > 0.f ? ee : 0.2f * ee;
            float wt = expf(ee - m);
            den += wt;
            acc += wt * hp[(size_t)t * C1];
        }
        out = acc / den;
    }
    out += bh[lane];
    xs[lane] = out > 0.f ? out : (expf(out) - 1.f);   // elu

    // gemm2 within the same wave (xs is wave-private)
    float acc2 = 0.f;
#pragma unroll 16
    for (int f = 0; f < C1; ++f) acc2 += xs[f] * Wo[f * FOUT + lane];
    h2[(size_t)bn * FOUT + lane] = acc2;
    float p = acc2 * ao[lane];
    float q = acc2 * ao[FOUT + lane];
    for (int o = 1; o < 64; o <<= 1) { p += __shfl_xor(p, o); q += __shfl_xor(q, o); }
    if (lane == 0) { s1o[bn] = p; s2o[bn] = q; }
}

// ---------------------------------------------------------------------------
// K3: layer-2 sparse attention -> TRANSPOSED out2T[b*FOUT+o][n].
// csr already deduped by K2 (-1 entries).
__global__ __launch_bounds__(256)
void k_att2(const float* __restrict__ h2, const float* __restrict__ s1o,
            const float* __restrict__ s2o, const float* __restrict__ bo,
            const int* __restrict__ cnt, const int* __restrict__ csr,
            float* __restrict__ out2T)
{
    __shared__ int tg4[4][MAXD];
    __shared__ float es4[4][FASTD];
    int tid = threadIdx.x, w = tid >> 6, lane = tid & 63;
    int* tg = tg4[w];
    int bn = blockIdx.x * 4 + w;
    int b = bn >> 11, n = bn & (NN - 1);

    int d = cnt[n]; if (d > MAXD) d = MAXD;
    for (int l = lane; l < d; l += 64) tg[l] = csr[n * MAXD + l];

    const float* hp = h2 + (size_t)b * NN * FOUT + lane;
    const float* s2p = s2o + b * NN;
    float out;
    if (d == 0) {
        float acc = 0.f;
        for (int j = 0; j < NN; ++j) acc += hp[(size_t)j * FOUT];
        out = acc * (1.0f / NN);
    } else if (d <= FASTD) {
        for (int l = lane; l < d; l += 64) {
            int t = tg[l];
            es4[w][l] = s2p[t < 0 ? 0 : t];
        }
        float s1 = s1o[bn];
        float m = -3.4e38f;
        for (int p = 0; p < d; ++p) {
            float ee = s1 + es4[w][p];
            ee = ee > 0.f ? ee : 0.2f * ee;
            m = fmaxf(m, tg[p] < 0 ? -3.4e38f : ee);
        }
        float den = 0.f, acc = 0.f;
        int p = 0;
        for (; p + 4 <= d; p += 4) {
            int t0 = tg[p], t1 = tg[p + 1], t2 = tg[p + 2], t3 = tg[p + 3];
            float v0 = hp[(size_t)(t0 < 0 ? 0 : t0) * FOUT];
            float v1 = hp[(size_t)(t1 < 0 ? 0 : t1) * FOUT];
            float v2 = hp[(size_t)(t2 < 0 ? 0 : t2) * FOUT];
            float v3 = hp[(size_t)(t3 < 0 ? 0 : t3) * FOUT];
            float e0 = s1 + es4[w][p + 0]; e0 = e0 > 0.f ? e0 : 0.2f * e0;
            float e1 = s1 + es4[w][p + 1]; e1 = e1 > 0.f ? e1 : 0.2f * e1;
            float e2 = s1 + es4[w][p + 2]; e2 = e2 > 0.f ? e2 : 0.2f * e2;
            float e3 = s1 + es4[w][p + 3]; e3 = e3 > 0.f ? e3 : 0.2f * e3;
            float w0 = t0 < 0 ? 0.f : expf(e0 - m);
            float w1 = t1 < 0 ? 0.f : expf(e1 - m);
            float w2 = t2 < 0 ? 0.f : expf(e2 - m);
            float w3 = t3 < 0 ? 0.f : expf(e3 - m);
            den += w0; acc += w0 * v0;
            den += w1; acc += w1 * v1;
            den += w2; acc += w2 * v2;
            den += w3; acc += w3 * v3;
        }
        for (; p < d; ++p) {
            int t = tg[p];
            float v = hp[(size_t)(t < 0 ? 0 : t) * FOUT];
            float ee = s1 + es4[w][p];
            ee = ee > 0.f ? ee : 0.2f * ee;
            float wt = t < 0 ? 0.f : expf(ee - m);
            den += wt; acc += wt * v;
        }
        out = acc / den;
    } else {
        float s1 = s1o[bn];
        float m = -3.4e38f;
        for (int p = 0; p < d; ++p) {
            int t = tg[p]; if (t < 0) continue;
            float ee = s1 + s2p[t];
            ee = ee > 0.f ? ee : 0.2f * ee;
            m = fmaxf(m, ee);
        }
        float den = 0.f, acc = 0.f;
        for (int p = 0; p < d; ++p) {
            int t = tg[p]; if (t < 0) continue;
            float ee = s1 + s2p[t];
            ee = ee > 0.f ? ee : 0.2f * ee;
            float wt = expf(ee - m);
            den += wt;
            acc += wt * hp[(size_t)t * FOUT];
        }
        out = acc / den;
    }
    out2T[(size_t)(b * FOUT + lane) * NN + n] = out + bo[lane];
}

// ---------------------------------------------------------------------------
// K4: fused logsumexp over node axis + subtract + store. grid = B*FOUT = 128.
__global__ __launch_bounds__(256)
void k_lsef(const float* __restrict__ out2T, float* __restrict__ out)
{
    int row = blockIdx.x;               // = b*FOUT + o
    int b = row >> 6, o = row & 63;
    int tid = threadIdx.x;
    const float* p = out2T + (size_t)row * NN;
    float v[8];
    float m = -3.4e38f;
#pragma unroll
    for (int j = 0; j < 8; ++j) {
        v[j] = p[tid + 256 * j];
        m = fmaxf(m, v[j]);
    }
    for (int off = 1; off < 64; off <<= 1) m = fmaxf(m, __shfl_xor(m, off));
    __shared__ float sm[4], ss[4];
    if ((tid & 63) == 0) sm[tid >> 6] = m;
    __syncthreads();
    float M = fmaxf(fmaxf(sm[0], sm[1]), fmaxf(sm[2], sm[3]));
    float sum = 0.f;
#pragma unroll
    for (int j = 0; j < 8; ++j) sum += expf(v[j] - M);
    for (int off = 1; off < 64; off <<= 1) sum += __shfl_xor(sum, off);
    if ((tid & 63) == 0) ss[tid >> 6] = sum;
    __syncthreads();
    float lse = M + logf(ss[0] + ss[1] + ss[2] + ss[3]);
    float* op = out + (size_t)b * NN * FOUT + o;
#pragma unroll
    for (int j = 0; j < 8; ++j) op[(size_t)(tid + 256 * j) * FOUT] = v[j] - lse;
}

// ---------------------------------------------------------------------------
extern "C" void kernel_launch(void* const* d_in, const int* in_sizes, int n_in,
                              void* d_out, int out_size, void* d_ws, size_t ws_size,
                              hipStream_t stream)
{
    (void)n_in; (void)out_size; (void)ws_size;
    const float* x     = (const float*)d_in[0];
    const int*   edges = (const int*)d_in[1];
    const float* Wh    = (const float*)d_in[2];
    const float* ah    = (const float*)d_in[3];
    const float* bh    = (const float*)d_in[4];
    const float* Wo    = (const float*)d_in[5];
    const float* ao    = (const float*)d_in[6];
    const float* bo    = (const float*)d_in[7];
    int E = in_sizes[1] / 2;

    char* w = (char*)d_ws;
    float* h1    = (float*)w; w += (size_t)BB * NN * C1 * 4;     // 1 MB
    float* s1h   = (float*)w; w += (size_t)BB * NN * HH * 4;     // 128 KB  [b][n][h]
    float* s2h   = (float*)w; w += (size_t)BB * NN * HH * 4;     // 128 KB  [b][n][h]
    float* h2    = (float*)w; w += (size_t)BB * NN * FOUT * 4;   // 1 MB
    float* s1o   = (float*)w; w += (size_t)BB * NN * 4;
    float* s2o   = (float*)w; w += (size_t)BB * NN * 4;
    float* out2T = (float*)w; w += (size_t)BB * FOUT * NN * 4;   // 1 MB
    int*   cnt   = (int*)w;   w += (size_t)NN * 4;
    int*   csr   = (int*)w;   w += (size_t)NN * MAXD * 4;        // 1.5 MB

    hipMemsetAsync(cnt, 0, (size_t)NN * 4, stream);

    int scatter_blocks = (E + 255) / 256;   // 128
    k_front <<<GB1 + scatter_blocks, 256, 0, stream>>>(x, Wh, ah, edges, E,
                                                       h1, s1h, s2h, cnt, csr);
    k_att1g2<<<BB * NN / 4, 256, 0, stream>>>(h1, s1h, s2h, bh, cnt, csr,
                                              Wo, ao, h2, s1o, s2o);
    k_att2  <<<BB * NN / 4, 256, 0, stream>>>(h2, s1o, s2o, bo, cnt, csr, out2T);
    k_lsef  <<<BB * FOUT, 256, 0, stream>>>(out2T, (float*)d_out);
}